// Round 6
// baseline (55.713 us; speedup 1.0000x reference)
//
#include <hip/hip_runtime.h>

#define BINS 10
#define TPB  256
#define NBLK 2048
#define TPB2 1024
#define NCOPY 16

// Packed per-bin accumulator: bits [48:63] = valid count, bits [0:47] = bce sum
// fixed-point 2^20. Per-copy bounds (16 lanes x 16 rows): count <= 256 < 2^16;
// sum <= 256 * ~13 * 2^20 < 2^32 << 2^48. No cross-field carry.
//
// C=2 algebra (exact, verified R4/R5): x0=(t==0?-p0:p0), x1=(t==0?p1:-p1):
//   g = m/(1+m), m = e0*e1 = exp(x0+x1)  (== |softmax - onehot| for both elems)
//   masked bce0+bce1 = log( (v0?1+e0:1) * (v1?1+e1:1) )
__device__ __forceinline__ unsigned long long ghm_pack(float p0, float p1, int t,
                                                       float w0, float w1, int* bin)
{
    bool tz = (t == 0);
    float x0 = tz ? -p0 : p0;
    float x1 = tz ?  p1 : -p1;
    float e0 = __expf(x0);
    float e1 = __expf(x1);
    float m  = e0 * e1;
    float g  = __fdividef(m, 1.0f + m);
    *bin = min((int)(g * 10.0f), BINS - 1);

    bool v0 = (w0 > 0.0f);
    bool v1 = (w1 > 0.0f);
    float a = v0 ? (1.0f + e0) : 1.0f;
    float b = v1 ? (1.0f + e1) : 1.0f;
    float wsum = __logf(a * b);
    unsigned long long cnt = (unsigned long long)((int)v0 + (int)v1);
    return (cnt << 48) | (unsigned long long)(unsigned int)(wsum * 1048576.0f + 0.5f);
}

__device__ __forceinline__ void ghm_2rows(float4 p, int2 t, float4 w,
                                          unsigned long long* hrow)
{
    int b0, b1;
    unsigned long long c0 = ghm_pack(p.x, p.y, t.x, w.x, w.y, &b0);
    unsigned long long c1 = ghm_pack(p.z, p.w, t.y, w.z, w.w, &b1);
    if (b0 == b1) {
        unsigned long long cs = c0 + c1;
        if (cs) atomicAdd(&hrow[b0], cs);
    } else {
        if (c0) atomicAdd(&hrow[b0], c0);
        if (c1) atomicAdd(&hrow[b1], c1);
    }
}

__global__ __launch_bounds__(TPB) void ghm_stage1(
    const float* __restrict__ pred, const int* __restrict__ target,
    const float* __restrict__ lw, unsigned long long* __restrict__ partialT, int B)
{
    __shared__ unsigned long long h[NCOPY][BINS];
    for (int k = threadIdx.x; k < NCOPY * BINS; k += TPB)
        ((unsigned long long*)h)[k] = 0ULL;
    __syncthreads();

    unsigned long long* hrow = h[threadIdx.x >> 4];

    const float4* p4 = (const float4*)pred;
    const float4* w4 = (const float4*)lw;
    const int2*   t2 = (const int2*)target;
    const int npairs = B >> 1;
    const int stride = (int)gridDim.x * TPB;
    const int i0 = blockIdx.x * TPB + threadIdx.x;

    if (npairs == 8 * stride) {
        // exact-fit: 8 pairs/thread, ALL 24 loads issued straight-line before
        // any use -> 24 outstanding vmem per wave (deep MLP probe).
        float4 P0 = p4[i0];
        float4 P1 = p4[i0 + stride];
        float4 P2 = p4[i0 + 2 * stride];
        float4 P3 = p4[i0 + 3 * stride];
        float4 P4 = p4[i0 + 4 * stride];
        float4 P5 = p4[i0 + 5 * stride];
        float4 P6 = p4[i0 + 6 * stride];
        float4 P7 = p4[i0 + 7 * stride];
        float4 W0 = w4[i0];
        float4 W1 = w4[i0 + stride];
        float4 W2 = w4[i0 + 2 * stride];
        float4 W3 = w4[i0 + 3 * stride];
        float4 W4 = w4[i0 + 4 * stride];
        float4 W5 = w4[i0 + 5 * stride];
        float4 W6 = w4[i0 + 6 * stride];
        float4 W7 = w4[i0 + 7 * stride];
        int2 T0 = t2[i0];
        int2 T1 = t2[i0 + stride];
        int2 T2 = t2[i0 + 2 * stride];
        int2 T3 = t2[i0 + 3 * stride];
        int2 T4 = t2[i0 + 4 * stride];
        int2 T5 = t2[i0 + 5 * stride];
        int2 T6 = t2[i0 + 6 * stride];
        int2 T7 = t2[i0 + 7 * stride];
        ghm_2rows(P0, T0, W0, hrow);
        ghm_2rows(P1, T1, W1, hrow);
        ghm_2rows(P2, T2, W2, hrow);
        ghm_2rows(P3, T3, W3, hrow);
        ghm_2rows(P4, T4, W4, hrow);
        ghm_2rows(P5, T5, W5, hrow);
        ghm_2rows(P6, T6, W6, hrow);
        ghm_2rows(P7, T7, W7, hrow);
    } else {
        // generic fallback (not hit for this problem's shape)
        for (int i = i0; i < npairs; i += stride)
            ghm_2rows(p4[i], t2[i], w4[i], hrow);
        if ((B & 1) && blockIdx.x == 0 && threadIdx.x == 0) {
            int r = B - 1;
            int bb;
            unsigned long long cc = ghm_pack(pred[2 * r], pred[2 * r + 1], target[r],
                                             lw[2 * r], lw[2 * r + 1], &bb);
            if (cc) atomicAdd(&h[0][bb], cc);
        }
    }
    __syncthreads();

    // transposed partials: [bin][block] so stage2 reads coalesced
    if (threadIdx.x < BINS) {
        unsigned long long v = 0;
#pragma unroll
        for (int c = 0; c < NCOPY; ++c) v += h[c][threadIdx.x];
        partialT[threadIdx.x * gridDim.x + blockIdx.x] = v;
    }
}

__global__ __launch_bounds__(TPB2) void ghm_stage2(
    const unsigned long long* __restrict__ partialT, float* __restrict__ out, int nb)
{
    double dsum[BINS], dcnt[BINS];
#pragma unroll
    for (int b = 0; b < BINS; ++b) { dsum[b] = 0.0; dcnt[b] = 0.0; }

    // coalesced independent burst: bin-major layout
#pragma unroll
    for (int b = 0; b < BINS; ++b) {
        for (int i = threadIdx.x; i < nb; i += TPB2) {
            unsigned long long p = partialT[b * nb + i];
            dcnt[b] += (double)(p >> 48);
            dsum[b] += (double)(p & ((1ULL << 48) - 1)) * (1.0 / 1048576.0);
        }
    }

#pragma unroll
    for (int b = 0; b < BINS; ++b) {
        for (int off = 32; off > 0; off >>= 1) {
            dsum[b] += __shfl_down(dsum[b], off);
            dcnt[b] += __shfl_down(dcnt[b], off);
        }
    }

    __shared__ double ss[TPB2 / 64][BINS];
    __shared__ double sc[TPB2 / 64][BINS];
    const int wid  = threadIdx.x >> 6;
    const int lane = threadIdx.x & 63;
    if (lane == 0) {
#pragma unroll
        for (int b = 0; b < BINS; ++b) { ss[wid][b] = dsum[b]; sc[wid][b] = dcnt[b]; }
    }
    __syncthreads();

    if (threadIdx.x == 0) {
        double loss = 0.0;
        int n = 0;
        for (int b = 0; b < BINS; ++b) {
            double S = 0.0, C = 0.0;
            for (int w = 0; w < TPB2 / 64; ++w) { S += ss[w][b]; C += sc[w][b]; }
            if (C > 0.0) { ++n; loss += S / C; }
        }
        if (n == 0) n = 1;
        out[0] = (float)(loss / (double)n);
    }
}

extern "C" void kernel_launch(void* const* d_in, const int* in_sizes, int n_in,
                              void* d_out, int out_size, void* d_ws, size_t ws_size,
                              hipStream_t stream)
{
    const float* pred   = (const float*)d_in[0];
    const int*   target = (const int*)d_in[1];
    const float* lw     = (const float*)d_in[2];
    const int B = in_sizes[1];

    int nb = NBLK;
    size_t need = (size_t)nb * BINS * sizeof(unsigned long long);
    if (ws_size < need) nb = (int)(ws_size / (BINS * sizeof(unsigned long long)));

    unsigned long long* partialT = (unsigned long long*)d_ws;

    ghm_stage1<<<nb, TPB, 0, stream>>>(pred, target, lw, partialT, B);
    ghm_stage2<<<1, TPB2, 0, stream>>>(partialT, (float*)d_out, nb);
}